// Round 8
// baseline (528.493 us; speedup 1.0000x reference)
//
#include <hip/hip_runtime.h>
#include <cstdint>
#include <cstddef>

#define B_ 2
#define S_ 2048
#define D_ 1024
#define H_ 16
#define DH_ 64
#define FF_ 4096
#define M_ (B_*S_)
#define MB_ ((size_t)1 << 20)

using u16 = unsigned short;
using short8 = __attribute__((ext_vector_type(8))) short;
using short4v = __attribute__((ext_vector_type(4))) short;
using floatx4 = __attribute__((ext_vector_type(4))) float;

__device__ __forceinline__ float bf2f(u16 u) {
    return __uint_as_float(((uint32_t)u) << 16);
}
__device__ __forceinline__ u16 f2bf(float f) {
    uint32_t u = __float_as_uint(f);
    u += 0x7fffu + ((u >> 16) & 1u);   // RNE
    return (u16)(u >> 16);
}
// async global->LDS, 16B per lane; LDS dest = wave-uniform base + lane*16
__device__ __forceinline__ void async_copy16(const u16* g, u16* l) {
    __builtin_amdgcn_global_load_lds(
        (const __attribute__((address_space(1))) uint32_t*)g,
        (__attribute__((address_space(3))) uint32_t*)l, 16, 0, 0);
}

// ---------------------------------------------------------------------------
// f32 -> bf16 elementwise convert (x). n multiple of 1024.
// ---------------------------------------------------------------------------
__global__ __launch_bounds__(256) void cvt_f32_bf16(
    const float* __restrict__ in, u16* __restrict__ out, int n)
{
    const int i = (blockIdx.x * 256 + threadIdx.x) * 4;
    if (i < n) {
        const float4 v = *(const float4*)(in + i);
        out[i + 0] = f2bf(v.x);
        out[i + 1] = f2bf(v.y);
        out[i + 2] = f2bf(v.z);
        out[i + 3] = f2bf(v.w);
    }
}

// ---------------------------------------------------------------------------
// mask (int32) -> additive f32 bias: 0 or -1e30
// ---------------------------------------------------------------------------
__global__ __launch_bounds__(256) void mask_bias(
    const int* __restrict__ mask, float* __restrict__ bias, int n)
{
    const int i = blockIdx.x * 256 + threadIdx.x;
    if (i < n) bias[i] = mask[i] ? 0.f : -1e30f;
}

// ---------------------------------------------------------------------------
// transpose+convert: in f32 (R x C) -> out bf16 (C x R)
// ---------------------------------------------------------------------------
__global__ void transpose_cvt(const float* __restrict__ in, u16* __restrict__ out,
                              int R, int C) {
    __shared__ float t[32][33];
    const int bx = blockIdx.x * 32, by = blockIdx.y * 32;
    const int tx = threadIdx.x, ty = threadIdx.y;
#pragma unroll
    for (int i = 0; i < 32; i += 8)
        t[ty + i][tx] = in[(size_t)(by + ty + i) * C + bx + tx];
    __syncthreads();
#pragma unroll
    for (int i = 0; i < 32; i += 8)
        out[(size_t)(bx + ty + i) * R + by + tx] = f2bf(t[tx][ty + i]);
}

// ---------------------------------------------------------------------------
// Generic GEMM: C(MxN) = A(MxK) @ W + bias; W as Wt (NxK bf16), bias f32.
// 128x128 tile, BK=32, 4 waves, mfma 16x16x32 bf16.
// ---------------------------------------------------------------------------
template<bool GELU, bool OUT_F32>
__global__ __launch_bounds__(256) void gemm_bt(
    const u16* __restrict__ A, const u16* __restrict__ Bt,
    const float* __restrict__ bias, void* __restrict__ Cout,
    int M, int N, int K)
{
    __shared__ alignas(16) u16 As[128 * 32];
    __shared__ alignas(16) u16 Bs[128 * 32];
    const int tid = threadIdx.x;
    const int w = tid >> 6, lane = tid & 63;
    const int lm = lane & 15, quad = lane >> 4;
    const int wm = w >> 1, wn = w & 1;
    const size_t m0 = (size_t)blockIdx.y * 128, n0 = (size_t)blockIdx.x * 128;

    const int rowS = w * 16 + (lane >> 2);
    const int colS = (lane & 3) * 8;
    const u16* gA = A + (m0 + rowS) * K + colS;
    const u16* gB = Bt + (n0 + rowS) * K + colS;
    u16* lA = As + w * 512;
    u16* lB = Bs + w * 512;

    floatx4 acc[4][4];
    const floatx4 z = {0.f, 0.f, 0.f, 0.f};
#pragma unroll
    for (int i = 0; i < 4; ++i)
#pragma unroll
        for (int j = 0; j < 4; ++j) acc[i][j] = z;

    for (int k0 = 0; k0 < K; k0 += 32) {
        __syncthreads();
        async_copy16(gA, lA);
        async_copy16(gA + (size_t)64 * K, lA + 2048);
        async_copy16(gB, lB);
        async_copy16(gB + (size_t)64 * K, lB + 2048);
        gA += 32; gB += 32;
        __syncthreads();

        short8 af[4], bfr[4];
#pragma unroll
        for (int t = 0; t < 4; ++t)
            af[t] = *(const short8*)&As[(wm * 64 + t * 16 + lm) * 32 + quad * 8];
#pragma unroll
        for (int t = 0; t < 4; ++t)
            bfr[t] = *(const short8*)&Bs[(wn * 64 + t * 16 + lm) * 32 + quad * 8];
#pragma unroll
        for (int i = 0; i < 4; ++i)
#pragma unroll
            for (int j = 0; j < 4; ++j)
                acc[i][j] = __builtin_amdgcn_mfma_f32_16x16x32_bf16(
                    af[i], bfr[j], acc[i][j], 0, 0, 0);
    }

#pragma unroll
    for (int i = 0; i < 4; ++i) {
        const size_t r0 = m0 + wm * 64 + i * 16 + quad * 4;
#pragma unroll
        for (int j = 0; j < 4; ++j) {
            const size_t c = n0 + wn * 64 + j * 16 + lm;
            const float bv = bias[c];
#pragma unroll
            for (int t = 0; t < 4; ++t) {
                float v = acc[i][j][t] + bv;
                if (GELU) v = 0.5f * v * (1.f + erff(v * 0.70710678118f));
                if (OUT_F32) ((float*)Cout)[(r0 + t) * (size_t)N + c] = v;
                else         ((u16*)Cout)[(r0 + t) * (size_t)N + c] = f2bf(v);
            }
        }
    }
}

// ---------------------------------------------------------------------------
// Small-N GEMM: 128x64 tile, BK=32, 4 waves stacked along M (each 32xN64).
// For N=1024 cases (Yproj, FFN2) -> 512 blocks instead of 256.
// ---------------------------------------------------------------------------
template<bool GELU, bool OUT_F32>
__global__ __launch_bounds__(256) void gemm_bt64(
    const u16* __restrict__ A, const u16* __restrict__ Bt,
    const float* __restrict__ bias, void* __restrict__ Cout,
    int M, int N, int K)
{
    __shared__ alignas(16) u16 As[128 * 32];
    __shared__ alignas(16) u16 Bs[64 * 32];
    const int tid = threadIdx.x;
    const int w = tid >> 6, lane = tid & 63;
    const int lm = lane & 15, quad = lane >> 4;
    const size_t m0 = (size_t)blockIdx.y * 128, n0 = (size_t)blockIdx.x * 64;

    const int rowS = w * 16 + (lane >> 2);
    const int colS = (lane & 3) * 8;
    const u16* gA = A + (m0 + rowS) * K + colS;
    const u16* gB = Bt + (n0 + rowS) * K + colS;
    u16* lA = As + w * 512;
    u16* lB = Bs + w * 512;

    floatx4 acc[2][4];
    const floatx4 z = {0.f, 0.f, 0.f, 0.f};
#pragma unroll
    for (int i = 0; i < 2; ++i)
#pragma unroll
        for (int j = 0; j < 4; ++j) acc[i][j] = z;

    for (int k0 = 0; k0 < K; k0 += 32) {
        __syncthreads();
        async_copy16(gA, lA);
        async_copy16(gA + (size_t)64 * K, lA + 2048);
        async_copy16(gB, lB);
        gA += 32; gB += 32;
        __syncthreads();

        short8 af[2], bfr[4];
#pragma unroll
        for (int i = 0; i < 2; ++i)
            af[i] = *(const short8*)&As[(w * 32 + i * 16 + lm) * 32 + quad * 8];
#pragma unroll
        for (int j = 0; j < 4; ++j)
            bfr[j] = *(const short8*)&Bs[(j * 16 + lm) * 32 + quad * 8];
#pragma unroll
        for (int i = 0; i < 2; ++i)
#pragma unroll
            for (int j = 0; j < 4; ++j)
                acc[i][j] = __builtin_amdgcn_mfma_f32_16x16x32_bf16(
                    af[i], bfr[j], acc[i][j], 0, 0, 0);
    }

#pragma unroll
    for (int i = 0; i < 2; ++i) {
        const size_t r0 = m0 + w * 32 + i * 16 + quad * 4;
#pragma unroll
        for (int j = 0; j < 4; ++j) {
            const size_t c = n0 + j * 16 + lm;
            const float bv = bias[c];
#pragma unroll
            for (int t = 0; t < 4; ++t) {
                float v = acc[i][j][t] + bv;
                if (GELU) v = 0.5f * v * (1.f + erff(v * 0.70710678118f));
                if (OUT_F32) ((float*)Cout)[(r0 + t) * (size_t)N + c] = v;
                else         ((u16*)Cout)[(r0 + t) * (size_t)N + c] = f2bf(v);
            }
        }
    }
}

// ---------------------------------------------------------------------------
// Fused QKV GEMM: A(M x 1024) @ Wqkv (1024 x 3072), Wqkvt rows: [WQ^T;WK^T;WV^T].
// Q,K written [m][1024]; V written transposed per head: Vt[((b*16+h)*64+dh)*S + s].
// ---------------------------------------------------------------------------
__global__ __launch_bounds__(256) void gemm_qkv(
    const u16* __restrict__ A, const u16* __restrict__ Bt,
    const float* __restrict__ bQ, const float* __restrict__ bK,
    const float* __restrict__ bV,
    u16* __restrict__ Qb, u16* __restrict__ Kb, u16* __restrict__ Vt)
{
    const int K = D_, N = 3 * D_;
    __shared__ alignas(16) u16 As[128 * 32];
    __shared__ alignas(16) u16 Bs[128 * 32];
    const int tid = threadIdx.x;
    const int w = tid >> 6, lane = tid & 63;
    const int lm = lane & 15, quad = lane >> 4;
    const int wm = w >> 1, wn = w & 1;
    const size_t m0 = (size_t)blockIdx.y * 128, n0 = (size_t)blockIdx.x * 128;

    const int rowS = w * 16 + (lane >> 2);
    const int colS = (lane & 3) * 8;
    const u16* gA = A + (m0 + rowS) * K + colS;
    const u16* gB = Bt + (n0 + rowS) * K + colS;
    u16* lA = As + w * 512;
    u16* lB = Bs + w * 512;

    floatx4 acc[4][4];
    const floatx4 z = {0.f, 0.f, 0.f, 0.f};
#pragma unroll
    for (int i = 0; i < 4; ++i)
#pragma unroll
        for (int j = 0; j < 4; ++j) acc[i][j] = z;

    for (int k0 = 0; k0 < K; k0 += 32) {
        __syncthreads();
        async_copy16(gA, lA);
        async_copy16(gA + (size_t)64 * K, lA + 2048);
        async_copy16(gB, lB);
        async_copy16(gB + (size_t)64 * K, lB + 2048);
        gA += 32; gB += 32;
        __syncthreads();

        short8 af[4], bfr[4];
#pragma unroll
        for (int t = 0; t < 4; ++t)
            af[t] = *(const short8*)&As[(wm * 64 + t * 16 + lm) * 32 + quad * 8];
#pragma unroll
        for (int t = 0; t < 4; ++t)
            bfr[t] = *(const short8*)&Bs[(wn * 64 + t * 16 + lm) * 32 + quad * 8];
#pragma unroll
        for (int i = 0; i < 4; ++i)
#pragma unroll
            for (int j = 0; j < 4; ++j)
                acc[i][j] = __builtin_amdgcn_mfma_f32_16x16x32_bf16(
                    af[i], bfr[j], acc[i][j], 0, 0, 0);
    }

#pragma unroll
    for (int i = 0; i < 4; ++i) {
        const size_t r0 = m0 + wm * 64 + i * 16 + quad * 4;
#pragma unroll
        for (int j = 0; j < 4; ++j) {
            const size_t c = n0 + wn * 64 + j * 16 + lm;
            const int sel = (int)(c >> 10);       // 0=Q 1=K 2=V (uniform per j)
            const int col = (int)(c & 1023);
            const float bv = sel == 0 ? bQ[col] : (sel == 1 ? bK[col] : bV[col]);
#pragma unroll
            for (int t = 0; t < 4; ++t) {
                const size_t r = r0 + t;
                const u16 v = f2bf(acc[i][j][t] + bv);
                if (sel == 0)      Qb[r * (size_t)D_ + col] = v;
                else if (sel == 1) Kb[r * (size_t)D_ + col] = v;
                else {
                    const int h = col >> 6, dh = col & 63;
                    const int bb = (int)(r >> 11), s = (int)(r & 2047);
                    Vt[((size_t)((bb * 16 + h) * 64 + dh)) * S_ + s] = v;
                }
            }
        }
    }
}

// ---------------------------------------------------------------------------
// Flash attention, S^T formulation, 128-key tiles, XOR-swizzled LDS.
// Kt[key][64dh]: 8-u16 block blk stored at blk^(key&7)  -> conflict-free b128.
// Vs[dh][128key]: block blk stored at blk^(dh&15)       -> balanced b64.
// S^T = K·Q^T; P^T consumed in-register by O^T += V^T·P^T (mfma 16x16x16).
// ---------------------------------------------------------------------------
__global__ __launch_bounds__(256) void attn_kernel(
    const u16* __restrict__ Q, const u16* __restrict__ Kg,
    const u16* __restrict__ Vt, const float* __restrict__ mbias,
    u16* __restrict__ O)
{
    __shared__ alignas(16) u16 Kt[128 * 64];
    __shared__ alignas(16) u16 Vs[64 * 128];
    const int tid = threadIdx.x, w = tid >> 6, lane = tid & 63;
    const int lm = lane & 15, quad = lane >> 4;
    const int b = blockIdx.y >> 4, h = blockIdx.y & 15;
    const int q0 = blockIdx.x * 64;
    const int m7 = lm & 7;

    // Q B-frag: n = lane&15 -> query, k = quad*8+j -> dh
    const u16* qp = Q + ((size_t)(b * S_ + q0 + w * 16 + lm)) * D_ + h * 64;
    const short8 bq0 = *(const short8*)(qp + quad * 8);
    const short8 bq1 = *(const short8*)(qp + 32 + quad * 8);

    // staging coords
    const int sr = tid >> 2;          // 0..63
    const int sc = tid & 3;           // 16-u16 chunk
    const u16* gK = Kg + ((size_t)(b * S_ + sr)) * D_ + h * 64 + sc * 16;
    const u16* gV = Vt + ((size_t)((b * 16 + h) * 64 + sr)) * S_ + sc * 16;
    const int mK = sr & 7;            // Kt swizzle mask (row&7; +64 preserves)
    const int mV = sr & 15;           // Vs swizzle mask
    const int cK = sc * 2;

    float mrow = -1e30f, lrow = 0.f;
    floatx4 o[4];
    const floatx4 z = {0.f, 0.f, 0.f, 0.f};
#pragma unroll
    for (int i = 0; i < 4; ++i) o[i] = z;

    const float* bp = mbias + b * S_;

    for (int kt = 0; kt < S_; kt += 128) {
        __syncthreads();
#pragma unroll
        for (int r = 0; r < 2; ++r) {
            const int row = sr + r * 64;
            const u16* srcK = gK + (size_t)(kt + r * 64) * D_;
            *(short8*)&Kt[row * 64 + ((cK ^ mK)) * 8]       = *(const short8*)srcK;
            *(short8*)&Kt[row * 64 + (((cK + 1) ^ mK)) * 8] = *(const short8*)(srcK + 8);
            const u16* srcV = gV + kt + r * 64;
            const int cV = cK + r * 8;
            *(short8*)&Vs[sr * 128 + ((cV ^ mV)) * 8]       = *(const short8*)srcV;
            *(short8*)&Vs[sr * 128 + (((cV + 1) ^ mV)) * 8] = *(const short8*)(srcV + 8);
        }
        __syncthreads();

        // S^T (128 keys x 16 queries): A = K-frag, B = Q-frag
        floatx4 st[8];
#pragma unroll
        for (int ks = 0; ks < 8; ++ks) {
            floatx4 s = z;
            const int krow = (ks * 16 + lm) * 64;
            const short8 ak0 = *(const short8*)&Kt[krow + ((quad ^ m7)) * 8];
            const short8 ak1 = *(const short8*)&Kt[krow + (((quad + 4) ^ m7)) * 8];
            s = __builtin_amdgcn_mfma_f32_16x16x32_bf16(ak0, bq0, s, 0, 0, 0);
            s = __builtin_amdgcn_mfma_f32_16x16x32_bf16(ak1, bq1, s, 0, 0, 0);
            const float4 mb = *(const float4*)&bp[kt + ks * 16 + quad * 4];
            st[ks][0] = s[0] * 0.125f + mb.x;
            st[ks][1] = s[1] * 0.125f + mb.y;
            st[ks][2] = s[2] * 0.125f + mb.z;
            st[ks][3] = s[3] * 0.125f + mb.w;
        }
        // online softmax: 32 in-lane + cross-quad (xor 16, 32)
        float tm = st[0][0];
#pragma unroll
        for (int ks = 0; ks < 8; ++ks)
#pragma unroll
            for (int r = 0; r < 4; ++r) tm = fmaxf(tm, st[ks][r]);
        tm = fmaxf(tm, __shfl_xor(tm, 16));
        tm = fmaxf(tm, __shfl_xor(tm, 32));
        const float mn = fmaxf(mrow, tm);
        const float alpha = __expf(mrow - mn);
        mrow = mn;
        float rs = 0.f;
#pragma unroll
        for (int ks = 0; ks < 8; ++ks)
#pragma unroll
            for (int r = 0; r < 4; ++r) {
                const float p = __expf(st[ks][r] - mn);
                st[ks][r] = p; rs += p;
            }
        rs += __shfl_xor(rs, 16);
        rs += __shfl_xor(rs, 32);
        lrow = lrow * alpha + rs;
#pragma unroll
        for (int d = 0; d < 4; ++d) o[d] *= alpha;

        // P^T B-frags (16x16x16): k = quad*4+j (key), n = lm (query)
        short4v pb[8];
#pragma unroll
        for (int ks = 0; ks < 8; ++ks) {
            short4v t;
            t[0] = (short)f2bf(st[ks][0]);
            t[1] = (short)f2bf(st[ks][1]);
            t[2] = (short)f2bf(st[ks][2]);
            t[3] = (short)f2bf(st[ks][3]);
            pb[ks] = t;
        }
        // O^T += V^T · P^T ; V^T A-frag: m=dh=d*16+lm, k=key=ks*16+quad*4+j
#pragma unroll
        for (int d = 0; d < 4; ++d)
#pragma unroll
            for (int ks = 0; ks < 8; ++ks) {
                const int blk = (2 * ks + (quad >> 1)) ^ lm;
                const short4v av = *(const short4v*)&Vs[(d * 16 + lm) * 128 + blk * 8 + (quad & 1) * 4];
                o[d] = __builtin_amdgcn_mfma_f32_16x16x16bf16_1k(av, pb[ks], o[d], 0, 0, 0);
            }
    }
    // O^T C-layout: row=dh=quad*4+reg, col=query=lm -> 4 contiguous u16/store
    const float inv = 1.f / lrow;
    u16* op = O + ((size_t)(b * S_ + q0 + w * 16 + lm)) * D_ + h * 64 + quad * 4;
#pragma unroll
    for (int d = 0; d < 4; ++d) {
        short4v pk;
        pk[0] = (short)f2bf(o[d][0] * inv);
        pk[1] = (short)f2bf(o[d][1] * inv);
        pk[2] = (short)f2bf(o[d][2] * inv);
        pk[3] = (short)f2bf(o[d][3] * inv);
        *(short4v*)(op + d * 16) = pk;
    }
}

// ---------------------------------------------------------------------------
// out = LayerNorm(mainp + resid) * gamma + beta. gamma/beta f32.
// Safe for out == mainp (rows are block-disjoint; reads precede writes).
// ---------------------------------------------------------------------------
template<bool MAIN_F32, bool RESID_F32, bool OUT_F32>
__global__ __launch_bounds__(256) void add_ln(
    const void* __restrict__ mainp, const void* __restrict__ resid,
    const float* __restrict__ gamma, const float* __restrict__ beta,
    void* __restrict__ out)
{
    const int row = blockIdx.x;
    const size_t base = (size_t)row * D_;
    const int t = threadIdx.x;
    const int w = t >> 6, lane = t & 63;
    float v[4];
#pragma unroll
    for (int i = 0; i < 4; ++i) {
        const int c = i * 256 + t;
        const float mv = MAIN_F32 ? ((const float*)mainp)[base + c]
                                  : bf2f(((const u16*)mainp)[base + c]);
        const float rv = RESID_F32 ? ((const float*)resid)[base + c]
                                   : bf2f(((const u16*)resid)[base + c]);
        v[i] = mv + rv;
    }
    float s = v[0] + v[1] + v[2] + v[3];
#pragma unroll
    for (int off = 32; off >= 1; off >>= 1) s += __shfl_xor(s, off);
    __shared__ float red[8];
    if (lane == 0) red[w] = s;
    __syncthreads();
    const float mean = (red[0] + red[1] + red[2] + red[3]) * (1.0f / D_);
    float q = 0.f;
#pragma unroll
    for (int i = 0; i < 4; ++i) { const float dd = v[i] - mean; q += dd * dd; }
#pragma unroll
    for (int off = 32; off >= 1; off >>= 1) q += __shfl_xor(q, off);
    if (lane == 0) red[4 + w] = q;
    __syncthreads();
    const float var = (red[4] + red[5] + red[6] + red[7]) * (1.0f / D_);
    const float rstd = rsqrtf(var + 1e-5f);
#pragma unroll
    for (int i = 0; i < 4; ++i) {
        const int c = i * 256 + t;
        const float o = (v[i] - mean) * rstd * gamma[c] + beta[c];
        if (OUT_F32) ((float*)out)[base + c] = o;
        else         ((u16*)out)[base + c] = f2bf(o);
    }
}

// ---------------------------------------------------------------------------
extern "C" void kernel_launch(void* const* d_in, const int* in_sizes, int n_in,
                              void* d_out, int out_size, void* d_ws, size_t ws_size,
                              hipStream_t stream)
{
    const float* x   = (const float*)d_in[0];
    const int* mask  = (const int*)d_in[1];
    const float* WQ = (const float*)d_in[2];  const float* bQ = (const float*)d_in[3];
    const float* WK = (const float*)d_in[4];  const float* bK = (const float*)d_in[5];
    const float* WV = (const float*)d_in[6];  const float* bV = (const float*)d_in[7];
    const float* WY = (const float*)d_in[8];  const float* bY = (const float*)d_in[9];
    const float* ln1w = (const float*)d_in[10]; const float* ln1b = (const float*)d_in[11];
    const float* ln2w = (const float*)d_in[12]; const float* ln2b = (const float*)d_in[13];
    const float* W1 = (const float*)d_in[14]; const float* b1 = (const float*)d_in[15];
    const float* W2 = (const float*)d_in[16]; const float* b2 = (const float*)d_in[17];

    // Workspace (peak 48 MB + 16 KB bias):
    char* ws = (char*)d_ws;
    u16* xb    = (u16*)(ws + 0  * MB_);
    u16* Wqkvt = (u16*)(ws + 8  * MB_);        // 6 MB: [WQ^T; WK^T; WV^T]
    u16* Qb    = (u16*)(ws + 16 * MB_);
    u16* Kb    = (u16*)(ws + 24 * MB_);
    u16* Vt    = (u16*)(ws + 32 * MB_);        // [b][h][dh][s]
    u16* Yat   = (u16*)(ws + 40 * MB_);
    u16* WYt   = (u16*)(ws + 8  * MB_);        // after Wqkvt dead
    u16* Yp    = (u16*)(ws + 16 * MB_);        // after Qb dead
    u16* hbf   = (u16*)(ws + 8  * MB_);        // after WYt dead
    u16* W1t   = (u16*)(ws + 0  * MB_);        // after xb dead
    u16* G     = (u16*)(ws + 16 * MB_);        // after Yp/Kb/Vt/Yat dead
    u16* W2t   = (u16*)(ws + 0  * MB_);        // after W1t dead
    float* mb  = (float*)(ws + 48 * MB_);      // 16 KB mask bias

    const dim3 tb(32, 8);

    cvt_f32_bf16<<<(M_*D_)/1024, 256, 0, stream>>>(x, xb, M_*D_);
    mask_bias<<<(B_*S_)/256, 256, 0, stream>>>(mask, mb, B_*S_);
    transpose_cvt<<<dim3(D_/32, D_/32), tb, 0, stream>>>(WQ, Wqkvt,                 D_, D_);
    transpose_cvt<<<dim3(D_/32, D_/32), tb, 0, stream>>>(WK, Wqkvt + (size_t)D_*D_, D_, D_);
    transpose_cvt<<<dim3(D_/32, D_/32), tb, 0, stream>>>(WV, Wqkvt + (size_t)2*D_*D_, D_, D_);

    gemm_qkv<<<dim3(3*D_/128, M_/128), 256, 0, stream>>>(xb, Wqkvt, bQ, bK, bV, Qb, Kb, Vt);

    attn_kernel<<<dim3(S_/64, B_*H_), 256, 0, stream>>>(Qb, Kb, Vt, mb, Yat);

    transpose_cvt<<<dim3(D_/32, D_/32), tb, 0, stream>>>(WY, WYt, D_, D_);
    gemm_bt64<false,false><<<dim3(D_/64, M_/128), 256, 0, stream>>>(Yat, WYt, bY, Yp, M_, D_, D_);

    add_ln<false,true,false><<<M_, 256, 0, stream>>>(Yp, x, ln1w, ln1b, hbf);

    transpose_cvt<<<dim3(FF_/32, D_/32), tb, 0, stream>>>(W1, W1t, D_, FF_);
    gemm_bt<true,false><<<dim3(FF_/128, M_/128), 256, 0, stream>>>(hbf, W1t, b1, G, M_, FF_, D_);

    transpose_cvt<<<dim3(D_/32, FF_/32), tb, 0, stream>>>(W2, W2t, FF_, D_);
    gemm_bt64<false,true><<<dim3(D_/64, M_/128), 256, 0, stream>>>(G, W2t, b2, (float*)d_out, M_, D_, FF_);

    add_ln<true,false,true><<<M_, 256, 0, stream>>>((float*)d_out, hbf, ln2w, ln2b, d_out);
}